// Round 7
// baseline (816.470 us; speedup 1.0000x reference)
//
#include <hip/hip_runtime.h>
#include <hip/hip_bf16.h>

typedef __bf16 bf16;
typedef __bf16 bf16x8 __attribute__((ext_vector_type(8)));
typedef float f32x4 __attribute__((ext_vector_type(4)));
typedef unsigned int u32x2 __attribute__((ext_vector_type(2)));

#define DEVI static __device__ __forceinline__

static constexpr int Bn = 4, Cc = 192, Hh = 256, Wd = 256;
static constexpr int NHd = 6, HD = 32;
static constexpr int Mtot = Bn * Hh * Wd;          // 262144 pixels
static constexpr float EPSv = 1e-5f;

DEVI f32x4 mfma16(bf16x8 a, bf16x8 b, f32x4 c) {
    return __builtin_amdgcn_mfma_f32_16x16x32_bf16(a, b, c, 0, 0, 0);
}

DEVI unsigned cvtpk_bf16(float lo, float hi) {
    unsigned r;
    asm("v_cvt_pk_bf16_f32 %0, %1, %2" : "=v"(r) : "v"(lo), "v"(hi));
    return r;
}

// ---------------------------------------------------------------- K0: weights
// WT576[n][k]: rows 0..191 = Wq^T, rows 192..575 = Wkv^T.  WoT[n][k] = Wo^T.
__global__ __launch_bounds__(256) void k_prep(const float* Wq, const float* Wkv,
                                              const float* Wo, bf16* WT, bf16* WoT) {
    int idx = blockIdx.x * 256 + threadIdx.x;
    if (idx < 576 * 192) {
        int n = idx / 192, k = idx % 192;
        float v = (n < 192) ? Wq[k * 192 + n] : Wkv[k * 384 + (n - 192)];
        WT[idx] = (bf16)v;
    } else if (idx < 576 * 192 + 192 * 192) {
        int j = idx - 576 * 192;
        int n = j / 192, k = j % 192;
        WoT[j] = (bf16)Wo[k * 192 + n];
    }
}

// ---------------------------------------------------------------- K1a: LayerNorm only
// Block = 64 consecutive pixels, wave q owns channels [q*48, q*48+48) held in
// 6 bf16x8 registers. x read ONCE. 2KB LDS -> high occupancy.
__global__ __launch_bounds__(256, 2) void k_ln(const float* __restrict__ x,
                                               const float* __restrict__ gamma,
                                               const float* __restrict__ beta,
                                               bf16* __restrict__ ln) {
    __shared__ float red[2][4][64];
    int tid = threadIdx.x, q = tid >> 6, p = tid & 63;
    int base = blockIdx.x * 64;
    int b = base >> 16;
    int hw = base & 65535;
    int h = hw >> 8, w0 = hw & 255;

    const float* xb = x + ((size_t)(b * Cc + q * 48) * Hh + h) * Wd + w0 + p;
    bf16x8 st[6];
    float s = 0.f, s2 = 0.f;
#pragma unroll
    for (int i0 = 0; i0 < 6; ++i0) {
#pragma unroll
        for (int j = 0; j < 8; ++j) {
            float v = xb[(size_t)(i0 * 8 + j) * Hh * Wd];
            s += v; s2 += v * v; st[i0][j] = (bf16)v;
        }
    }
    red[0][q][p] = s; red[1][q][p] = s2;
    __syncthreads();
    float mu = (red[0][0][p] + red[0][1][p] + red[0][2][p] + red[0][3][p]) * (1.f / 192.f);
    float m2 = (red[1][0][p] + red[1][1][p] + red[1][2][p] + red[1][3][p]) * (1.f / 192.f);
    float rs = rsqrtf(m2 - mu * mu + EPSv);
    bf16* lr = ln + (size_t)(base + p) * Cc + q * 48;
#pragma unroll
    for (int i0 = 0; i0 < 6; ++i0) {
        bf16x8 o;
#pragma unroll
        for (int j = 0; j < 8; ++j) {
            int c = q * 48 + i0 * 8 + j;          // wave-uniform -> s_load
            o[j] = (bf16)(((float)st[i0][j] - mu) * rs * gamma[c] + beta[c]);
        }
        *(bf16x8*)(lr + i0 * 8) = o;
    }
}

// ---------------------------------------------------------------- K1b: QKV projection GEMM
// Block = 64 pixels. A-tile in LDS (XOR-swizzled, conflict-free, 24KB).
// 4 waves x 144 cols, m streamed (acc[9] live). Swapped mfma -> lane holds 4
// consecutive channels of one pixel; staged through KVs for 16B-line stores.
__global__ __launch_bounds__(256, 2) void k_qkv(const bf16* __restrict__ ln,
                                                const bf16* __restrict__ WT,
                                                const float* __restrict__ bq,
                                                const float* __restrict__ bkv,
                                                bf16* __restrict__ QKV) {
    constexpr int KS = 592;
    __shared__ __align__(16) bf16 A[64 * 192];
    __shared__ __align__(16) bf16 KVs[16 * KS];

    int tid = threadIdx.x, q = tid >> 6, p = tid & 63;
    int base = blockIdx.x * 64;

    // stage A: thread (q,p) copies channels [q*48,q*48+48) of pixel p,
    // XOR-swizzling 8-elem groups: group gi stored at gi^(row&7)
    const bf16* lr = ln + (size_t)(base + p) * Cc + q * 48;
#pragma unroll
    for (int gl = 0; gl < 6; ++gl) {
        bf16x8 v = *(const bf16x8*)(lr + gl * 8);
        int gi = q * 6 + gl;
        *(bf16x8*)&A[p * 192 + ((gi ^ (p & 7)) << 3)] = v;
    }
    __syncthreads();

    int lane = tid & 63, l15 = lane & 15, g = lane >> 4;
    const bf16* Wbase = WT + (size_t)(q * 144 + l15) * Cc + g * 8;
#pragma unroll 1
    for (int mt = 0; mt < 4; ++mt) {
        f32x4 acc[9] = {};
        int row = mt * 16 + l15;
#pragma unroll
        for (int kk = 0; kk < 6; ++kk) {
            int gi = kk * 4 + g;
            bf16x8 a = *(bf16x8*)&A[row * 192 + ((gi ^ (row & 7)) << 3)];
#pragma unroll
            for (int nt = 0; nt < 9; ++nt) {
                bf16x8 bb = *(const bf16x8*)(Wbase + (size_t)nt * 16 * Cc + kk * 32);
                acc[nt] = mfma16(bb, a, acc[nt]);   // D[n][pix]
            }
        }
        // stage: lane holds channels n0..n0+3 of pixel l15
#pragma unroll
        for (int nt = 0; nt < 9; ++nt) {
            int n0 = q * 144 + nt * 16 + g * 4;
            const float* bsrc = (n0 < 192) ? (bq + n0) : (bkv + n0 - 192);
            f32x4 b4 = *(const f32x4*)bsrc;
            u32x2 pk;
            pk[0] = cvtpk_bf16(acc[nt][0] + b4[0], acc[nt][1] + b4[1]);
            pk[1] = cvtpk_bf16(acc[nt][2] + b4[2], acc[nt][3] + b4[3]);
            *(u32x2*)&KVs[l15 * KS + n0] = pk;
        }
        __syncthreads();
        // coalesced write-out: 16 px x 72 chunks of 8 ch = 1152 x 16B
        int pixbase = base + mt * 16;
#pragma unroll
        for (int it = 0; it < 5; ++it) {
            int id = it * 256 + tid;
            if (id < 1152) {
                int pl = id / 72, ck = id - pl * 72;
                int n0 = ck * 8;
                bf16x8 v = *(bf16x8*)&KVs[pl * KS + n0];
                *(bf16x8*)(QKV + ((size_t)(n0 >> 5) * Mtot + (pixbase + pl)) * HD + (n0 & 31)) = v;
            }
        }
        __syncthreads();
    }
}

// ---------------------------------------------------------------- K2: attention
// One block per (head, window); 4 waves x 16 q-rows; kv = 256 overlapping rows.
// QK^T computed TRANSPOSED (A=K, B=Q): lane holds (kv=t*16+g*4+r, q=l15) ->
// whole-row softmax per lane, contiguous-kv b64 P writes, 4 shuffles total.
__global__ __launch_bounds__(256) void k_attn(const bf16* __restrict__ QKV,
                                              const float* __restrict__ bkv,
                                              bf16* __restrict__ O) {
    constexpr int PS = 268;                        // P stride: 536B, 8B-aligned rows
    int bid = blockIdx.x;
    bid = (bid & 7) * 3072 + (bid >> 3);          // chunked XCD swizzle (24576 = 8*3072)
    int head = bid >> 12;                          // /4096
    int win = bid & 4095;
    int b = win >> 10, wloc = win & 1023;
    int h0 = ((wloc >> 5) << 3), w0 = ((wloc & 31) << 3);
    bool interior = (h0 != 0) && (h0 != Hh - 8) && (w0 != 0) && (w0 != Wd - 8);

    int tid = threadIdx.x, wave = tid >> 6, lane = tid & 63;
    int l15 = lane & 15, g = lane >> 4;

    const bf16* Qh = QKV + (size_t)head * Mtot * HD;
    const bf16* Kh = QKV + (size_t)(6 + head) * Mtot * HD;
    const bf16* Vh = QKV + (size_t)(12 + head) * Mtot * HD;
    bf16* Oh = O + (size_t)head * Mtot * HD;
    long long p00 = (long long)(b * Hh + h0 - 4) * Wd + (w0 - 4);

    __shared__ __align__(16) bf16 VT[32 * 264];   // V^T [d][kv]
    __shared__ __align__(16) bf16 P[64 * PS];     // probs [qrow][kv] (unnormalized)

    // ---- stage V^T (one kv row per thread)
    if (interior) {
        int r = tid;
        const bf16* vr = Vh + (p00 + (r >> 4) * Wd + (r & 15)) * HD;
#pragma unroll
        for (int d0 = 0; d0 < 32; d0 += 8) {
            bf16x8 v8 = *(const bf16x8*)(vr + d0);
#pragma unroll
            for (int j = 0; j < 8; ++j) VT[(d0 + j) * 264 + r] = v8[j];
        }
    } else {
        int r = tid;
        int ph = h0 - 4 + (r >> 4), pw = w0 - 4 + (r & 15);
        bool ok = ((unsigned)ph < (unsigned)Hh) && ((unsigned)pw < (unsigned)Wd);
        long long pix = ok ? ((long long)(b * Hh + ph) * Wd + pw) : 0;
        const bf16* vr = Vh + pix * HD;
        const float* vb = bkv + Cc + head * HD;
#pragma unroll
        for (int d0 = 0; d0 < 32; d0 += 8) {
            bf16x8 v8 = *(const bf16x8*)(vr + d0);
#pragma unroll
            for (int j = 0; j < 8; ++j) VT[(d0 + j) * 264 + r] = ok ? v8[j] : (bf16)vb[d0 + j];
        }
    }

    // ---- Q fragment (B-operand now): lane l15 holds Q row wave*16+l15
    int qr = wave * 16 + l15;
    size_t qpix = (size_t)(b * Hh + h0 + (qr >> 3)) * Wd + w0 + (qr & 7);
    bf16x8 aq = *(const bf16x8*)(Qh + qpix * HD + g * 8);
    bf16x8 kb;
#pragma unroll
    for (int j = 0; j < 8; ++j) kb[j] = (bf16)bkv[head * HD + g * 8 + j];
    __syncthreads();

    // ---- S^T = K @ Q^T : 16 kv-tiles; lane -> (kv = t*16+g*4+r, q = l15)
    f32x4 s[16];
    const f32x4 z = {0.f, 0.f, 0.f, 0.f};
    const bf16* kp = Kh + (p00 + l15) * HD + g * 8;
    if (interior) {
#pragma unroll
        for (int t = 0; t < 16; ++t) {
            bf16x8 kf = *(const bf16x8*)(kp + (size_t)t * Wd * HD);
            s[t] = mfma16(kf, aq, z);
        }
    } else {
        bool colok = ((unsigned)(w0 - 4 + l15) < (unsigned)Wd);
#pragma unroll
        for (int t = 0; t < 16; ++t) {
            int ph = h0 - 4 + t;                  // wave-uniform
            bf16x8 kf;
            if ((unsigned)ph < (unsigned)Hh) {
                kf = *(const bf16x8*)(kp + (size_t)t * Wd * HD);
                kf = colok ? kf : kb;
            } else {
                kf = kb;
            }
            s[t] = mfma16(kf, aq, z);
        }
    }

    // ---- softmax: each lane owns full row q=l15 (64 of 256 kv; rest in xor-16/32 lanes)
    const float sc = 0.17677669529663689f * 1.4426950408889634f; // scale * log2(e)
    float mr0 = fmaxf(s[0][0], s[0][1]), mr1 = fmaxf(s[0][2], s[0][3]);
#pragma unroll
    for (int t = 1; t < 16; ++t) {
        mr0 = fmaxf(mr0, fmaxf(s[t][0], s[t][1]));
        mr1 = fmaxf(mr1, fmaxf(s[t][2], s[t][3]));
    }
    float m = fmaxf(mr0, mr1);
    m = fmaxf(m, __shfl_xor(m, 16));
    m = fmaxf(m, __shfl_xor(m, 32));
    float sr0 = 0.f, sr1 = 0.f, sr2 = 0.f, sr3 = 0.f;
    int prow = wave * 16 + l15;
#pragma unroll
    for (int t = 0; t < 16; ++t) {
        float p0 = __builtin_amdgcn_exp2f((s[t][0] - m) * sc);
        float p1 = __builtin_amdgcn_exp2f((s[t][1] - m) * sc);
        float p2 = __builtin_amdgcn_exp2f((s[t][2] - m) * sc);
        float p3 = __builtin_amdgcn_exp2f((s[t][3] - m) * sc);
        sr0 += p0; sr1 += p1; sr2 += p2; sr3 += p3;
        u32x2 pk;
        pk[0] = cvtpk_bf16(p0, p1);
        pk[1] = cvtpk_bf16(p2, p3);
        *(u32x2*)&P[prow * PS + t * 16 + g * 4] = pk;
    }
    float sum = (sr0 + sr1) + (sr2 + sr3);
    sum += __shfl_xor(sum, 16);
    sum += __shfl_xor(sum, 32);
    float inv = __builtin_amdgcn_rcpf(sum);
    __builtin_amdgcn_wave_barrier();   // P rows are wave-private; ordering only

    // ---- O = P @ V (normalize at epilogue)
    f32x4 o[2] = {};
#pragma unroll
    for (int kk = 0; kk < 8; ++kk) {
        bf16x8 ap = *(const bf16x8*)(&P[prow * PS + kk * 32 + g * 8]);
#pragma unroll
        for (int nt = 0; nt < 2; ++nt) {
            bf16x8 bv = *(const bf16x8*)(&VT[(nt * 16 + l15) * 264 + kk * 32 + g * 8]);
            o[nt] = mfma16(ap, bv, o[nt]);
        }
    }
    // inv for epilogue rows g*4+r lives in lanes with l15 == g*4+r (same g ok)
    float invr[4];
#pragma unroll
    for (int r = 0; r < 4; ++r)
        invr[r] = __shfl(inv, (lane & 48) | (g * 4 + r));
#pragma unroll
    for (int nt = 0; nt < 2; ++nt)
#pragma unroll
        for (int r = 0; r < 4; ++r) {
            int row = wave * 16 + g * 4 + r;
            size_t pix = (size_t)(b * Hh + h0 + (row >> 3)) * Wd + w0 + (row & 7);
            Oh[pix * HD + nt * 16 + l15] = (bf16)(o[nt][r] * invr[r]);
        }
}

// ---------------------------------------------------------------- K3: O-proj + residual (BHWC->BCHW)
// A is head-major AO[plane=c>>5][pix][32]; GEMM k-slice kk == plane.
__global__ __launch_bounds__(256) void k_out(const bf16* __restrict__ AO,
                                             const bf16* __restrict__ WoT,
                                             const float* __restrict__ bo,
                                             const float* __restrict__ x,
                                             float* __restrict__ out) {
    int row0 = blockIdx.x * 64;
    int tid = threadIdx.x, wave = tid >> 6, lane = tid & 63;
    int l15 = lane & 15, g = lane >> 4;
    int nb = wave * 48;
    f32x4 acc[4][3] = {};
    const bf16* Arow[4];
#pragma unroll
    for (int mt = 0; mt < 4; ++mt) Arow[mt] = AO + (size_t)(row0 + mt * 16 + l15) * HD + g * 8;
    const bf16* Wrow[3];
#pragma unroll
    for (int nt = 0; nt < 3; ++nt) Wrow[nt] = WoT + (size_t)(nb + nt * 16 + l15) * Cc + g * 8;
#pragma unroll
    for (int kk = 0; kk < 6; ++kk) {
        bf16x8 a[4];
#pragma unroll
        for (int mt = 0; mt < 4; ++mt)
            a[mt] = *(const bf16x8*)(Arow[mt] + (size_t)kk * Mtot * HD);
#pragma unroll
        for (int nt = 0; nt < 3; ++nt) {
            bf16x8 bb = *(const bf16x8*)(Wrow[nt] + kk * 32);
#pragma unroll
            for (int mt = 0; mt < 4; ++mt) acc[mt][nt] = mfma16(a[mt], bb, acc[mt][nt]);
        }
    }
    __shared__ float st[192 * 65];
#pragma unroll
    for (int nt = 0; nt < 3; ++nt) {
        float bval = bo[nb + nt * 16 + l15];
#pragma unroll
        for (int mt = 0; mt < 4; ++mt)
#pragma unroll
            for (int r = 0; r < 4; ++r) {
                int ccol = nb + nt * 16 + l15;
                int px = mt * 16 + g * 4 + r;
                st[ccol * 65 + px] = acc[mt][nt][r] + bval;
            }
    }
    __syncthreads();
    int bb2 = row0 / (Hh * Wd);
    int rem = row0 % (Hh * Wd);
    int h = rem / Wd, wstart = rem % Wd;
    for (int idx = tid; idx < 192 * 64; idx += 256) {
        int cc = idx >> 6, px = idx & 63;
        size_t ga = ((size_t)(bb2 * Cc + cc) * Hh + h) * Wd + wstart + px;
        out[ga] = st[cc * 65 + px] + x[ga];
    }
}

// ---------------------------------------------------------------- launch
extern "C" void kernel_launch(void* const* d_in, const int* in_sizes, int n_in,
                              void* d_out, int out_size, void* d_ws, size_t ws_size,
                              hipStream_t stream) {
    const float* x     = (const float*)d_in[0];
    const float* gamma = (const float*)d_in[1];
    const float* beta  = (const float*)d_in[2];
    const float* Wq    = (const float*)d_in[3];
    const float* bq    = (const float*)d_in[4];
    const float* Wkv   = (const float*)d_in[5];
    const float* bkv   = (const float*)d_in[6];
    const float* Wo    = (const float*)d_in[7];
    const float* bo    = (const float*)d_in[8];
    float* out = (float*)d_out;

    char* ws = (char*)d_ws;
    constexpr size_t PLANE = (size_t)Mtot * HD * 2;        // 16777216 B
    bf16* QKV = (bf16*)(ws);                                // 18 planes = 301989888 B
    bf16* AO  = (bf16*)(ws + 18 * PLANE);                   // 6 planes  = 100663296 B
    bf16* LN  = AO;                                         // alias: dead before k_attn writes AO
    bf16* WT  = (bf16*)(ws + 24 * PLANE);                   // 221184 B
    bf16* WoT = (bf16*)(ws + 24 * PLANE + 221184);          // 73728 B

    k_prep<<<576, 256, 0, stream>>>(Wq, Wkv, Wo, WT, WoT);
    k_ln<<<Mtot / 64, 256, 0, stream>>>(x, gamma, beta, LN);
    k_qkv<<<Mtot / 64, 256, 0, stream>>>(LN, WT, bq, bkv, QKV);
    k_attn<<<4096 * NHd, 256, 0, stream>>>(QKV, bkv, AO);
    k_out<<<Mtot / 64, 256, 0, stream>>>(AO, WoT, bo, x, out);
}

// Round 8
// 553.421 us; speedup vs baseline: 1.4753x; 1.4753x over previous
//
#include <hip/hip_runtime.h>
#include <hip/hip_bf16.h>

typedef __bf16 bf16;
typedef __bf16 bf16x8 __attribute__((ext_vector_type(8)));
typedef float f32x4 __attribute__((ext_vector_type(4)));
typedef unsigned int u32x2 __attribute__((ext_vector_type(2)));

#define DEVI static __device__ __forceinline__

static constexpr int Bn = 4, Cc = 192, Hh = 256, Wd = 256;
static constexpr int NHd = 6, HD = 32;
static constexpr int Mtot = Bn * Hh * Wd;          // 262144 pixels
static constexpr float EPSv = 1e-5f;

DEVI f32x4 mfma16(bf16x8 a, bf16x8 b, f32x4 c) {
    return __builtin_amdgcn_mfma_f32_16x16x32_bf16(a, b, c, 0, 0, 0);
}

DEVI unsigned cvtpk_bf16(float lo, float hi) {
    unsigned r;
    asm("v_cvt_pk_bf16_f32 %0, %1, %2" : "=v"(r) : "v"(lo), "v"(hi));
    return r;
}

// ---------------------------------------------------------------- K0: weights
// WT576[n][k]: rows 0..191 = Wq^T, rows 192..575 = Wkv^T.  WoT[n][k] = Wo^T.
__global__ __launch_bounds__(256) void k_prep(const float* Wq, const float* Wkv,
                                              const float* Wo, bf16* WT, bf16* WoT) {
    int idx = blockIdx.x * 256 + threadIdx.x;
    if (idx < 576 * 192) {
        int n = idx / 192, k = idx % 192;
        float v = (n < 192) ? Wq[k * 192 + n] : Wkv[k * 384 + (n - 192)];
        WT[idx] = (bf16)v;
    } else if (idx < 576 * 192 + 192 * 192) {
        int j = idx - 576 * 192;
        int n = j / 192, k = j % 192;
        WoT[j] = (bf16)Wo[k * 192 + n];
    }
}

// ---------------------------------------------------------------- K1: fused LN + QKV projection
// Block = 64 consecutive pixels. Pass1: read x once, f32 stats + bf16 A-tile.
// Pass2: normalize A in LDS. GEMM: nt-OUTER streaming -> each W fragment
// loaded exactly ONCE per wave (1x L2 traffic, vs 4x when mt was outer).
// acc[4] live only (16 regs). Swapped mfma -> lane holds 4 consecutive
// channels of one pixel -> direct 8B packed stores to head-major planes.
__global__ __launch_bounds__(256) void k_lnqkv(const float* __restrict__ x,
                                               const float* __restrict__ gamma,
                                               const float* __restrict__ beta,
                                               const bf16* __restrict__ WT,
                                               const float* __restrict__ bq,
                                               const float* __restrict__ bkv,
                                               bf16* __restrict__ QKV) {
    constexpr int AS = 200;                       // A-tile stride
    __shared__ __align__(16) bf16 A[64 * AS];
    __shared__ float red[2][4][64];
    __shared__ float sg[Cc], sbv[Cc];

    int tid = threadIdx.x;
    int q = tid >> 6, p = tid & 63;
    int base = blockIdx.x * 64;
    int b = base >> 16;
    int hw = base & 65535;
    int h = hw >> 8, w0 = hw & 255;
    if (tid < Cc) { sg[tid] = gamma[tid]; sbv[tid] = beta[tid]; }

    // pass 1: 48 channels per wave; stats in f32, stash bf16 copy in A
    const float* xb = x + ((size_t)(b * Cc + q * 48) * Hh + h) * Wd + w0 + p;
    float s = 0.f, s2 = 0.f;
#pragma unroll
    for (int i0 = 0; i0 < 48; i0 += 8) {
        bf16x8 o;
#pragma unroll
        for (int j = 0; j < 8; ++j) {
            float v = xb[(size_t)(i0 + j) * Hh * Wd];
            s += v; s2 += v * v; o[j] = (bf16)v;
        }
        *(bf16x8*)&A[p * AS + q * 48 + i0] = o;
    }
    red[0][q][p] = s; red[1][q][p] = s2;
    __syncthreads();
    float mu = (red[0][0][p] + red[0][1][p] + red[0][2][p] + red[0][3][p]) * (1.f / 192.f);
    float m2 = (red[1][0][p] + red[1][1][p] + red[1][2][p] + red[1][3][p]) * (1.f / 192.f);
    float rs = rsqrtf(m2 - mu * mu + EPSv);
    // pass 2: normalize in place
#pragma unroll
    for (int i0 = 0; i0 < 48; i0 += 8) {
        bf16x8 v8 = *(bf16x8*)&A[p * AS + q * 48 + i0];
        bf16x8 o;
#pragma unroll
        for (int j = 0; j < 8; ++j) {
            int c = q * 48 + i0 + j;
            o[j] = (bf16)(((float)v8[j] - mu) * rs * sg[c] + sbv[c]);
        }
        *(bf16x8*)&A[p * AS + q * 48 + i0] = o;
    }
    __syncthreads();

    // GEMM: 4 waves x 144 cols; nt streamed OUTER (W read once), mt inner.
    int lane = tid & 63, l15 = lane & 15, g = lane >> 4;
    const bf16* Wbase = WT + (size_t)(q * 144 + l15) * Cc + g * 8;
#pragma unroll 1
    for (int nt = 0; nt < 9; ++nt) {
        f32x4 acc[4] = {};
        const bf16* wp = Wbase + (size_t)nt * 16 * Cc;
#pragma unroll
        for (int kk = 0; kk < 6; ++kk) {
            bf16x8 wb = *(const bf16x8*)(wp + kk * 32);
#pragma unroll
            for (int mt = 0; mt < 4; ++mt) {
                bf16x8 a = *(bf16x8*)&A[(mt * 16 + l15) * AS + kk * 32 + g * 8];
                acc[mt] = mfma16(wb, a, acc[mt]);   // D[n][pix]
            }
        }
        int n0 = q * 144 + nt * 16 + g * 4;         // 4-group never crosses plane
        const float* bsrc = (n0 < 192) ? (bq + n0) : (bkv + n0 - 192);
        f32x4 b4 = *(const f32x4*)bsrc;
        bf16* outp = QKV + (size_t)(n0 >> 5) * Mtot * HD + (n0 & 31);
#pragma unroll
        for (int mt = 0; mt < 4; ++mt) {
            u32x2 pk;
            pk[0] = cvtpk_bf16(acc[mt][0] + b4[0], acc[mt][1] + b4[1]);
            pk[1] = cvtpk_bf16(acc[mt][2] + b4[2], acc[mt][3] + b4[3]);
            *(u32x2*)(outp + (size_t)(base + mt * 16 + l15) * HD) = pk;
        }
    }
}

// ---------------------------------------------------------------- K2: attention
// One block per (head, window); 4 waves x 16 q-rows; kv = 256 overlapping rows.
// QK^T computed TRANSPOSED (A=K, B=Q): lane holds (kv=t*16+g*4+r, q=l15) ->
// whole-row softmax per lane, contiguous-kv b64 P writes, 4 shuffles total.
__global__ __launch_bounds__(256) void k_attn(const bf16* __restrict__ QKV,
                                              const float* __restrict__ bkv,
                                              bf16* __restrict__ O) {
    constexpr int PS = 268;                        // P stride: 536B, 8B-aligned rows
    int bid = blockIdx.x;
    bid = (bid & 7) * 3072 + (bid >> 3);          // chunked XCD swizzle (24576 = 8*3072)
    int head = bid >> 12;                          // /4096
    int win = bid & 4095;
    int b = win >> 10, wloc = win & 1023;
    int h0 = ((wloc >> 5) << 3), w0 = ((wloc & 31) << 3);
    bool interior = (h0 != 0) && (h0 != Hh - 8) && (w0 != 0) && (w0 != Wd - 8);

    int tid = threadIdx.x, wave = tid >> 6, lane = tid & 63;
    int l15 = lane & 15, g = lane >> 4;

    const bf16* Qh = QKV + (size_t)head * Mtot * HD;
    const bf16* Kh = QKV + (size_t)(6 + head) * Mtot * HD;
    const bf16* Vh = QKV + (size_t)(12 + head) * Mtot * HD;
    bf16* Oh = O + (size_t)head * Mtot * HD;
    long long p00 = (long long)(b * Hh + h0 - 4) * Wd + (w0 - 4);

    __shared__ __align__(16) bf16 VT[32 * 264];   // V^T [d][kv]
    __shared__ __align__(16) bf16 P[64 * PS];     // probs [qrow][kv] (unnormalized)

    // ---- stage V^T (one kv row per thread)
    if (interior) {
        int r = tid;
        const bf16* vr = Vh + (p00 + (r >> 4) * Wd + (r & 15)) * HD;
#pragma unroll
        for (int d0 = 0; d0 < 32; d0 += 8) {
            bf16x8 v8 = *(const bf16x8*)(vr + d0);
#pragma unroll
            for (int j = 0; j < 8; ++j) VT[(d0 + j) * 264 + r] = v8[j];
        }
    } else {
        int r = tid;
        int ph = h0 - 4 + (r >> 4), pw = w0 - 4 + (r & 15);
        bool ok = ((unsigned)ph < (unsigned)Hh) && ((unsigned)pw < (unsigned)Wd);
        long long pix = ok ? ((long long)(b * Hh + ph) * Wd + pw) : 0;
        const bf16* vr = Vh + pix * HD;
        const float* vb = bkv + Cc + head * HD;
#pragma unroll
        for (int d0 = 0; d0 < 32; d0 += 8) {
            bf16x8 v8 = *(const bf16x8*)(vr + d0);
#pragma unroll
            for (int j = 0; j < 8; ++j) VT[(d0 + j) * 264 + r] = ok ? v8[j] : (bf16)vb[d0 + j];
        }
    }

    // ---- Q fragment (B-operand now): lane l15 holds Q row wave*16+l15
    int qr = wave * 16 + l15;
    size_t qpix = (size_t)(b * Hh + h0 + (qr >> 3)) * Wd + w0 + (qr & 7);
    bf16x8 aq = *(const bf16x8*)(Qh + qpix * HD + g * 8);
    bf16x8 kb;
#pragma unroll
    for (int j = 0; j < 8; ++j) kb[j] = (bf16)bkv[head * HD + g * 8 + j];
    __syncthreads();

    // ---- S^T = K @ Q^T : 16 kv-tiles; lane -> (kv = t*16+g*4+r, q = l15)
    f32x4 s[16];
    const f32x4 z = {0.f, 0.f, 0.f, 0.f};
    const bf16* kp = Kh + (p00 + l15) * HD + g * 8;
    if (interior) {
#pragma unroll
        for (int t = 0; t < 16; ++t) {
            bf16x8 kf = *(const bf16x8*)(kp + (size_t)t * Wd * HD);
            s[t] = mfma16(kf, aq, z);
        }
    } else {
        bool colok = ((unsigned)(w0 - 4 + l15) < (unsigned)Wd);
#pragma unroll
        for (int t = 0; t < 16; ++t) {
            int ph = h0 - 4 + t;                  // wave-uniform
            bf16x8 kf;
            if ((unsigned)ph < (unsigned)Hh) {
                kf = *(const bf16x8*)(kp + (size_t)t * Wd * HD);
                kf = colok ? kf : kb;
            } else {
                kf = kb;
            }
            s[t] = mfma16(kf, aq, z);
        }
    }

    // ---- softmax: each lane owns full row q=l15 (64 of 256 kv; rest in xor-16/32 lanes)
    const float sc = 0.17677669529663689f * 1.4426950408889634f; // scale * log2(e)
    float mr0 = fmaxf(s[0][0], s[0][1]), mr1 = fmaxf(s[0][2], s[0][3]);
#pragma unroll
    for (int t = 1; t < 16; ++t) {
        mr0 = fmaxf(mr0, fmaxf(s[t][0], s[t][1]));
        mr1 = fmaxf(mr1, fmaxf(s[t][2], s[t][3]));
    }
    float m = fmaxf(mr0, mr1);
    m = fmaxf(m, __shfl_xor(m, 16));
    m = fmaxf(m, __shfl_xor(m, 32));
    float sr0 = 0.f, sr1 = 0.f, sr2 = 0.f, sr3 = 0.f;
    int prow = wave * 16 + l15;
#pragma unroll
    for (int t = 0; t < 16; ++t) {
        float p0 = __builtin_amdgcn_exp2f((s[t][0] - m) * sc);
        float p1 = __builtin_amdgcn_exp2f((s[t][1] - m) * sc);
        float p2 = __builtin_amdgcn_exp2f((s[t][2] - m) * sc);
        float p3 = __builtin_amdgcn_exp2f((s[t][3] - m) * sc);
        sr0 += p0; sr1 += p1; sr2 += p2; sr3 += p3;
        u32x2 pk;
        pk[0] = cvtpk_bf16(p0, p1);
        pk[1] = cvtpk_bf16(p2, p3);
        *(u32x2*)&P[prow * PS + t * 16 + g * 4] = pk;
    }
    float sum = (sr0 + sr1) + (sr2 + sr3);
    sum += __shfl_xor(sum, 16);
    sum += __shfl_xor(sum, 32);
    float inv = __builtin_amdgcn_rcpf(sum);
    __builtin_amdgcn_wave_barrier();   // P rows are wave-private; ordering only

    // ---- O = P @ V (normalize at epilogue)
    f32x4 o[2] = {};
#pragma unroll
    for (int kk = 0; kk < 8; ++kk) {
        bf16x8 ap = *(const bf16x8*)(&P[prow * PS + kk * 32 + g * 8]);
#pragma unroll
        for (int nt = 0; nt < 2; ++nt) {
            bf16x8 bv = *(const bf16x8*)(&VT[(nt * 16 + l15) * 264 + kk * 32 + g * 8]);
            o[nt] = mfma16(ap, bv, o[nt]);
        }
    }
    // inv for epilogue rows g*4+r lives in lanes with l15 == g*4+r (same g ok)
    float invr[4];
#pragma unroll
    for (int r = 0; r < 4; ++r)
        invr[r] = __shfl(inv, (lane & 48) | (g * 4 + r));
#pragma unroll
    for (int nt = 0; nt < 2; ++nt)
#pragma unroll
        for (int r = 0; r < 4; ++r) {
            int row = wave * 16 + g * 4 + r;
            size_t pix = (size_t)(b * Hh + h0 + (row >> 3)) * Wd + w0 + (row & 7);
            Oh[pix * HD + nt * 16 + l15] = (bf16)(o[nt][r] * invr[r]);
        }
}

// ---------------------------------------------------------------- K3: O-proj + residual (BHWC->BCHW)
// A is head-major AO[plane=c>>5][pix][32]; GEMM k-slice kk == plane.
__global__ __launch_bounds__(256) void k_out(const bf16* __restrict__ AO,
                                             const bf16* __restrict__ WoT,
                                             const float* __restrict__ bo,
                                             const float* __restrict__ x,
                                             float* __restrict__ out) {
    int row0 = blockIdx.x * 64;
    int tid = threadIdx.x, wave = tid >> 6, lane = tid & 63;
    int l15 = lane & 15, g = lane >> 4;
    int nb = wave * 48;
    f32x4 acc[4][3] = {};
    const bf16* Arow[4];
#pragma unroll
    for (int mt = 0; mt < 4; ++mt) Arow[mt] = AO + (size_t)(row0 + mt * 16 + l15) * HD + g * 8;
    const bf16* Wrow[3];
#pragma unroll
    for (int nt = 0; nt < 3; ++nt) Wrow[nt] = WoT + (size_t)(nb + nt * 16 + l15) * Cc + g * 8;
#pragma unroll
    for (int kk = 0; kk < 6; ++kk) {
        bf16x8 a[4];
#pragma unroll
        for (int mt = 0; mt < 4; ++mt)
            a[mt] = *(const bf16x8*)(Arow[mt] + (size_t)kk * Mtot * HD);
#pragma unroll
        for (int nt = 0; nt < 3; ++nt) {
            bf16x8 bb = *(const bf16x8*)(Wrow[nt] + kk * 32);
#pragma unroll
            for (int mt = 0; mt < 4; ++mt) acc[mt][nt] = mfma16(a[mt], bb, acc[mt][nt]);
        }
    }
    __shared__ float st[192 * 65];
#pragma unroll
    for (int nt = 0; nt < 3; ++nt) {
        float bval = bo[nb + nt * 16 + l15];
#pragma unroll
        for (int mt = 0; mt < 4; ++mt)
#pragma unroll
            for (int r = 0; r < 4; ++r) {
                int ccol = nb + nt * 16 + l15;
                int px = mt * 16 + g * 4 + r;
                st[ccol * 65 + px] = acc[mt][nt][r] + bval;
            }
    }
    __syncthreads();
    int bb2 = row0 / (Hh * Wd);
    int rem = row0 % (Hh * Wd);
    int h = rem / Wd, wstart = rem % Wd;
    for (int idx = tid; idx < 192 * 64; idx += 256) {
        int cc = idx >> 6, px = idx & 63;
        size_t ga = ((size_t)(bb2 * Cc + cc) * Hh + h) * Wd + wstart + px;
        out[ga] = st[cc * 65 + px] + x[ga];
    }
}

// ---------------------------------------------------------------- launch
extern "C" void kernel_launch(void* const* d_in, const int* in_sizes, int n_in,
                              void* d_out, int out_size, void* d_ws, size_t ws_size,
                              hipStream_t stream) {
    const float* x     = (const float*)d_in[0];
    const float* gamma = (const float*)d_in[1];
    const float* beta  = (const float*)d_in[2];
    const float* Wq    = (const float*)d_in[3];
    const float* bq    = (const float*)d_in[4];
    const float* Wkv   = (const float*)d_in[5];
    const float* bkv   = (const float*)d_in[6];
    const float* Wo    = (const float*)d_in[7];
    const float* bo    = (const float*)d_in[8];
    float* out = (float*)d_out;

    char* ws = (char*)d_ws;
    constexpr size_t PLANE = (size_t)Mtot * HD * 2;        // 16777216 B
    bf16* QKV = (bf16*)(ws);                                // 18 planes = 301989888 B
    bf16* AO  = (bf16*)(ws + 18 * PLANE);                   // 6 planes  = 100663296 B
    bf16* WT  = (bf16*)(ws + 24 * PLANE);                   // 221184 B
    bf16* WoT = (bf16*)(ws + 24 * PLANE + 221184);          // 73728 B

    k_prep<<<576, 256, 0, stream>>>(Wq, Wkv, Wo, WT, WoT);
    k_lnqkv<<<Mtot / 64, 256, 0, stream>>>(x, gamma, beta, WT, bq, bkv, QKV);
    k_attn<<<4096 * NHd, 256, 0, stream>>>(QKV, bkv, AO);
    k_out<<<Mtot / 64, 256, 0, stream>>>(AO, WoT, bo, x, out);
}